// Round 1
// baseline (1555.893 us; speedup 1.0000x reference)
//
#include <hip/hip_runtime.h>

// out[i] = state[i]*W[0] + neighbor_sum[i]*W[1] + b
// neighbor_sum[dst] += state[src] over 32M edges (scatter-add via atomics).

__global__ __launch_bounds__(256) void gnn_zero(float* __restrict__ ws, int n) {
    int i = blockIdx.x * blockDim.x + threadIdx.x;
    if (i < n) ws[i] = 0.0f;
}

__global__ __launch_bounds__(256) void gnn_scatter(const float* __restrict__ state,
                                                   const int* __restrict__ src,
                                                   const int* __restrict__ dst,
                                                   float* __restrict__ nsum,
                                                   int n_edges) {
    const int tid = blockIdx.x * blockDim.x + threadIdx.x;
    const int stride = gridDim.x * blockDim.x;
    const int n4 = n_edges >> 2;
    const int4* __restrict__ src4 = (const int4*)src;
    const int4* __restrict__ dst4 = (const int4*)dst;
    for (int i = tid; i < n4; i += stride) {
        int4 s = src4[i];
        int4 d = dst4[i];
        float vx = state[s.x];
        float vy = state[s.y];
        float vz = state[s.z];
        float vw = state[s.w];
        atomicAdd(&nsum[d.x], vx);
        atomicAdd(&nsum[d.y], vy);
        atomicAdd(&nsum[d.z], vz);
        atomicAdd(&nsum[d.w], vw);
    }
    // tail (n_edges not multiple of 4)
    for (int i = (n4 << 2) + tid; i < n_edges; i += stride) {
        atomicAdd(&nsum[dst[i]], state[src[i]]);
    }
}

__global__ __launch_bounds__(256) void gnn_finalize(const float* __restrict__ state,
                                                    const float* __restrict__ nsum,
                                                    const float* __restrict__ W,
                                                    const float* __restrict__ b,
                                                    float* __restrict__ out, int n) {
    int i = blockIdx.x * blockDim.x + threadIdx.x;
    if (i < n) {
        out[i] = fmaf(state[i], W[0], fmaf(nsum[i], W[1], b[0]));
    }
}

extern "C" void kernel_launch(void* const* d_in, const int* in_sizes, int n_in,
                              void* d_out, int out_size, void* d_ws, size_t ws_size,
                              hipStream_t stream) {
    const float* state = (const float*)d_in[0];
    const int*   esrc  = (const int*)d_in[1];
    const int*   edst  = (const int*)d_in[2];
    const float* W     = (const float*)d_in[3];
    const float* b     = (const float*)d_in[4];
    float* out = (float*)d_out;

    const int n_nodes = in_sizes[0];      // 1,000,000
    const int n_edges = in_sizes[1];      // 32,000,000

    float* nsum = (float*)d_ws;           // 4 MB scratch

    // 1) zero neighbor_sum (ws is poisoned 0xAA and not re-poisoned between replays)
    {
        int blocks = (n_nodes + 255) / 256;
        gnn_zero<<<blocks, 256, 0, stream>>>(nsum, n_nodes);
    }

    // 2) scatter-add over edges; grid-stride, capped grid (G11)
    {
        int work = n_edges >> 2;                       // int4-vectorized items
        int blocks = (work + 255) / 256;
        if (blocks > 2048) blocks = 2048;
        gnn_scatter<<<blocks, 256, 0, stream>>>(state, esrc, edst, nsum, n_edges);
    }

    // 3) finalize: out = state*W00 + nsum*W01 + b
    {
        int blocks = (n_nodes + 255) / 256;
        gnn_finalize<<<blocks, 256, 0, stream>>>(state, nsum, W, b, out, n_nodes);
    }
}